// Round 3
// baseline (1370.371 us; speedup 1.0000x reference)
//
#include <hip/hip_runtime.h>
#include <hip/hip_fp16.h>

#define N 128
#define INF_ 1e9f

// float -> order-preserving u32 (ascending); NaN sorts above all finite values
__device__ __forceinline__ unsigned f2ord(float f) {
    unsigned b = __float_as_uint(f);
    return b ^ ((unsigned)((int)b >> 31) | 0x80000000u);
}
__device__ __forceinline__ float ord2f(unsigned k) {
    unsigned b = k ^ ((unsigned)((int)(~k) >> 31) | 0x80000000u);
    return __uint_as_float(b);
}
template <int CTRL>
__device__ __forceinline__ int dppmov(int v) {
    return __builtin_amdgcn_update_dpp(v, v, CTRL, 0xF, 0xF, false);
}
__device__ __forceinline__ unsigned rlu(unsigned v, int lane) {
    return (unsigned)__builtin_amdgcn_readlane((int)v, lane);
}
__device__ __forceinline__ int rli(int v, int lane) {
    return __builtin_amdgcn_readlane(v, lane);
}
__device__ __forceinline__ unsigned uminu(unsigned a, unsigned b) { return a < b ? a : b; }

// top-2 merge level over DPP row_ror<CTRL>; carries (k1=min,q1=argcol, k2=min2,q2=argcol2)
#define LEVQ(CTRL) { \
    unsigned ok1 = (unsigned)dppmov<CTRL>((int)k1); \
    int      oq1 = dppmov<CTRL>(q1); \
    unsigned ok2 = (unsigned)dppmov<CTRL>((int)k2); \
    int      oq2 = dppmov<CTRL>(q2); \
    unsigned mx; int mq; \
    if (ok1 < k1 || (ok1 == k1 && oq1 < q1)) { mx = k1; mq = q1; k1 = ok1; q1 = oq1; } \
    else { mx = ok1; mq = oq1; } \
    if (ok2 < k2 || (ok2 == k2 && oq2 < q2)) { k2 = ok2; q2 = oq2; } \
    if (mx < k2 || (mx == k2 && mq < q2))    { k2 = mx;  q2 = mq; } \
}
// scalar top-2 merge of group (B1,Bq1,B2,Bq2) into (A1,Aq1,A2,Aq2)
#define MRGG(B1,Bq1,B2,Bq2) { \
    unsigned mx; int mq; \
    if (B1 < A1 || (B1 == A1 && Bq1 < Aq1)) { mx = A1; mq = Aq1; A1 = B1; Aq1 = Bq1; } \
    else { mx = B1; mq = Bq1; } \
    if (B2 < A2 || (B2 == A2 && Bq2 < Aq2)) { A2 = B2; Aq2 = Bq2; } \
    if (mx < A2 || (mx == A2 && mq < Aq2))  { A2 = mx; Aq2 = mq; } \
}

// One batch per 64-lane wave. Lane l owns columns c0=l+1, c1=l+65 (1-based).
__global__ void __launch_bounds__(64) lsa_solve_kernel(
        const float* __restrict__ x, const float* __restrict__ bias,
        float* __restrict__ out, int B) {
    __shared__ unsigned Cs[N][64];       // packed fp16 costs (= -x)
    __shared__ float u_lds[N + 1];
    __shared__ int   p_lds[N + 1];       // p[j] = row assigned to col j, 0 = free
    __shared__ int   way_lds[N + 1];     // also reused as float v-shadow (vsh) pre-SAP
    __shared__ int   colOf[N + 1];       // row -> col (0 = free row)
    __shared__ int   freeQ[N + 1];       // claim arbitration, then free-row queue

    const int b = blockIdx.x;
    const int l = threadIdx.x;
    const int c0 = l + 1, c1 = l + 65;
    const unsigned long long mlt = (1ull << l) - 1;
    const float* xb = x + (size_t)b * (N * N);

    // ---- stage costs into LDS (coalesced, fp16-packed) ----
    #pragma unroll 4
    for (int r = 0; r < N; ++r) {
        float v0 = xb[r * N + l];
        float v1 = xb[r * N + l + 64];
        __half2 h = __floats2half2_rn(-v0, -v1);   // minimize -x
        Cs[r][l] = __builtin_bit_cast(unsigned, h);
    }
    u_lds[l] = 0.f;  u_lds[l + 64] = 0.f;
    p_lds[l] = 0;    p_lds[l + 64] = 0;
    colOf[l] = 0;    colOf[l + 64] = 0;
    freeQ[l] = 0x7FFFFFFF; freeQ[l + 64] = 0x7FFFFFFF;
    if (l == 0) { u_lds[128] = 0.f; p_lds[128] = 0; colOf[128] = 0; freeQ[128] = 0x7FFFFFFF; }
    __syncthreads();

    // ---- Phase A: column reduction + greedy claim ----
    float m0 = INF_, m1 = INF_; int am0 = 1, am1 = 1;
    #pragma unroll 1
    for (int r = 0; r < N; ++r) {
        __half2 h = __builtin_bit_cast(__half2, Cs[r][l]);
        float f0 = __low2float(h), f1 = __high2float(h);
        if (f0 < m0) { m0 = f0; am0 = r + 1; }
        if (f1 < m1) { m1 = f1; am1 = r + 1; }
    }
    float v0r = m0, v1r = m1;            // v[j] = column minimum
    atomicMin(&freeQ[am0], c0);          // freeQ doubles as rowOwner here
    atomicMin(&freeQ[am1], c1);
    __syncthreads();
    {
        int w0 = (freeQ[am0] == c0) ? am0 : 0;
        int w1 = (freeQ[am1] == c1) ? am1 : 0;
        p_lds[c0] = w0;
        p_lds[c1] = w1;
        if (w0) colOf[am0] = c0;
        if (w1) colOf[am1] = c1;
    }
    __syncthreads();

    // ---- Phase B: reduction transfer (Jacobi: old-v reads, deferred distinct-col writes) ----
    {
        float pend0 = 0.f, pend1 = 0.f;
        #pragma unroll 2
        for (int r = 1; r <= N; ++r) {
            int j1 = colOf[r];
            __half2 h = __builtin_bit_cast(__half2, Cs[r - 1][l]);
            float rc0 = __low2float(h)  - v0r;
            float rc1 = __high2float(h) - v1r;
            if (c0 == j1) rc0 = INF_;
            if (c1 == j1) rc1 = INF_;
            unsigned k = uminu(f2ord(rc0), f2ord(rc1));
            k = uminu(k, (unsigned)dppmov<0x121>((int)k));
            k = uminu(k, (unsigned)dppmov<0x122>((int)k));
            k = uminu(k, (unsigned)dppmov<0x124>((int)k));
            k = uminu(k, (unsigned)dppmov<0x128>((int)k));
            unsigned ga = rlu(k, 0), gb = rlu(k, 16), gc = rlu(k, 32), gd = rlu(k, 48);
            float m2 = ord2f(uminu(uminu(ga, gb), uminu(gc, gd)));
            if (j1 != 0) {
                if (c0 == j1) pend0 = m2;
                if (c1 == j1) pend1 = m2;
            }
        }
        v0r -= pend0; v1r -= pend1;
    }

    // ---- Phase C: augmenting row reduction (LAPJV, 2 passes) ----
    int numfree;
    {
        int fA = (colOf[l + 1] == 0);
        int fB = (colOf[l + 65] == 0);
        unsigned long long bA = __ballot(fA);
        unsigned long long bB = __ballot(fB);
        int nA = __popcll(bA);
        if (fA) freeQ[__popcll(bA & mlt)] = l + 1;
        if (fB) freeQ[nA + __popcll(bB & mlt)] = l + 65;
        numfree = nA + __popcll(bB);
    }
    __syncthreads();
    #pragma unroll 1
    for (int pass = 0; pass < 2; ++pass) {
        int kk = 0, prv = numfree;
        numfree = 0;
        int guard = 0;
        #pragma unroll 1
        while (kk < prv && ++guard <= 4 * N) {
            const int i = freeQ[kk++];
            __half2 h = __builtin_bit_cast(__half2, Cs[i - 1][l]);
            float rc0 = __low2float(h)  - v0r;
            float rc1 = __high2float(h) - v1r;
            unsigned o0 = f2ord(rc0), o1 = f2ord(rc1);
            unsigned k1, k2; int q1, q2;
            if (o0 <= o1) { k1 = o0; q1 = c0; k2 = o1; q2 = c1; }
            else          { k1 = o1; q1 = c1; k2 = o0; q2 = c0; }
            LEVQ(0x121) LEVQ(0x122) LEVQ(0x124) LEVQ(0x128)
            unsigned A1 = rlu(k1, 0);  int Aq1 = rli(q1, 0);
            unsigned A2 = rlu(k2, 0);  int Aq2 = rli(q2, 0);
            { unsigned B1=rlu(k1,16); int Bq1=rli(q1,16); unsigned B2=rlu(k2,16); int Bq2=rli(q2,16); MRGG(B1,Bq1,B2,Bq2) }
            { unsigned B1=rlu(k1,32); int Bq1=rli(q1,32); unsigned B2=rlu(k2,32); int Bq2=rli(q2,32); MRGG(B1,Bq1,B2,Bq2) }
            { unsigned B1=rlu(k1,48); int Bq1=rli(q1,48); unsigned B2=rlu(k2,48); int Bq2=rli(q2,48); MRGG(B1,Bq1,B2,Bq2) }
            int j1 = Aq1;
            bool strict = (A1 < A2);             // umin < usubmin
            int i0 = p_lds[j1];
            if (strict) {
                float d = ord2f(A2) - ord2f(A1);
                if (c0 == j1) v0r -= d;
                if (c1 == j1) v1r -= d;
            } else if (i0 != 0) {
                j1 = Aq2;                        // exact tie: take second-best column
                i0 = p_lds[j1];
            }
            if (l == 0) {
                p_lds[j1] = i;
                colOf[i] = j1;
                if (i0 != 0) colOf[i0] = 0;
            }
            if (i0 != 0) {
                if (strict) { --kk; if (l == 0) freeQ[kk] = i0; }      // reprocess now
                else        { if (l == 0) freeQ[numfree] = i0; ++numfree; }  // next pass
            }
            __syncthreads();
        }
    }

    // ---- Phase D: recompute u = C - v on assigned pairs; free rows keep u = 0 ----
    {
        float* vsh = (float*)way_lds;
        vsh[c0] = v0r;
        vsh[c1] = v1r;
        __syncthreads();
        int r0 = l + 1, r1 = l + 65;
        int ja = colOf[r0];
        float uA = 0.f;
        if (ja) {
            __half2 h = __builtin_bit_cast(__half2, Cs[r0 - 1][(ja - 1) & 63]);
            uA = ((ja <= 64) ? __low2float(h) : __high2float(h)) - vsh[ja];
        }
        u_lds[r0] = uA;
        int jb = colOf[r1];
        float uB = 0.f;
        if (jb) {
            __half2 h = __builtin_bit_cast(__half2, Cs[r1 - 1][(jb - 1) & 63]);
            uB = ((jb <= 64) ? __low2float(h) : __high2float(h)) - vsh[jb];
        }
        u_lds[r1] = uB;
    }
    __syncthreads();

    // rebuild free-row list for SAP
    int nf2;
    {
        int fA = (colOf[l + 1] == 0);
        int fB = (colOf[l + 65] == 0);
        unsigned long long bA = __ballot(fA);
        unsigned long long bB = __ballot(fB);
        int nA = __popcll(bA);
        if (fA) freeQ[__popcll(bA & mlt)] = l + 1;
        if (fB) freeQ[nA + __popcll(bB & mlt)] = l + 65;
        nf2 = nA + __popcll(bB);
    }
    __syncthreads();

    int prow0 = p_lds[c0]; float uprow0 = u_lds[prow0];
    int prow1 = p_lds[c1]; float uprow1 = u_lds[prow1];

    // ---- Phase E: SAP augmentation for remaining free rows (round-2 inner loop) ----
    #pragma unroll 1
    for (int fi = 0; fi < nf2; ++fi) {
        const int i = freeQ[fi];

        float dist0 = INF_, dist1 = INF_;             // absolute distances (minv + cum)
        int   way0 = 0, way1 = 0;
        float cumAt0 = 0.f, cumAt1 = 0.f;
        float cum = 0.f, base = 0.f;                  // base = cum - u[i0]; u[root]=0
        int   j0 = 0, i0 = i;

        #pragma unroll 1
        for (int it = 0; it <= N; ++it) {
            if (c0 == j0) { cumAt0 = cum; dist0 = __int_as_float(0x7FC00000); }
            if (c1 == j0) { cumAt1 = cum; dist1 = __int_as_float(0x7FC00000); }

            __half2 h = __builtin_bit_cast(__half2, Cs[i0 - 1][l]);
            float cand0 = __low2float(h)  - v0r + base;   // C - u[i0] - v[j] + cum
            float cand1 = __high2float(h) - v1r + base;
            if (cand0 < dist0) { dist0 = cand0; way0 = j0; }
            if (cand1 < dist1) { dist1 = cand1; way1 = j0; }

            unsigned k0 = f2ord(dist0), k1 = f2ord(dist1);
            unsigned key; int cp; int uub;
            if (k1 < k0) { key = k1; cp = (c1 << 8) | prow1; uub = __float_as_int(uprow1); }
            else         { key = k0; cp = (c0 << 8) | prow0; uub = __float_as_int(uprow0); }

            { unsigned ok=(unsigned)dppmov<0x121>((int)key); int oc=dppmov<0x121>(cp), ou=dppmov<0x121>(uub);
              if (ok < key) { key=ok; cp=oc; uub=ou; } }
            { unsigned ok=(unsigned)dppmov<0x122>((int)key); int oc=dppmov<0x122>(cp), ou=dppmov<0x122>(uub);
              if (ok < key) { key=ok; cp=oc; uub=ou; } }
            { unsigned ok=(unsigned)dppmov<0x124>((int)key); int oc=dppmov<0x124>(cp), ou=dppmov<0x124>(uub);
              if (ok < key) { key=ok; cp=oc; uub=ou; } }
            { unsigned ok=(unsigned)dppmov<0x128>((int)key); int oc=dppmov<0x128>(cp), ou=dppmov<0x128>(uub);
              if (ok < key) { key=ok; cp=oc; uub=ou; } }

            unsigned gk0 = rlu(key, 0);  int gc0 = rli(cp, 0),  gu0 = rli(uub, 0);
            unsigned gk1 = rlu(key, 16); int gc1 = rli(cp, 16), gu1 = rli(uub, 16);
            unsigned gk2 = rlu(key, 32); int gc2 = rli(cp, 32), gu2 = rli(uub, 32);
            unsigned gk3 = rlu(key, 48); int gc3 = rli(cp, 48), gu3 = rli(uub, 48);
            unsigned kw = gk0; int cw = gc0, uw = gu0;
            if (gk1 < kw || (gk1 == kw && gc1 < cw)) { kw = gk1; cw = gc1; uw = gu1; }
            if (gk2 < kw || (gk2 == kw && gc2 < cw)) { kw = gk2; cw = gc2; uw = gu2; }
            if (gk3 < kw || (gk3 == kw && gc3 < cw)) { kw = gk3; cw = gc3; uw = gu3; }

            cum  = ord2f(kw);
            j0   = cw >> 8;
            i0   = cw & 0xFF;
            base = cum - __int_as_float(uw);
            if (i0 == 0) break;                        // reached a free column
        }

        // deferred potential updates
        bool used0 = (__float_as_uint(dist0) == 0x7FC00000u);
        bool used1 = (__float_as_uint(dist1) == 0x7FC00000u);
        if (used0) { float dv = cum - cumAt0; v0r -= dv; u_lds[prow0] += dv; }
        if (used1) { float dv = cum - cumAt1; v1r -= dv; u_lds[prow1] += dv; }
        way_lds[c0] = way0; way_lds[c1] = way1;
        if (l == 0) { u_lds[i] += cum; p_lds[0] = i; }
        __syncthreads();

        // augment along the path (serial, lane 0)
        if (l == 0) {
            int j = j0;
            for (int s = 0; s <= N && j != 0; ++s) {
                int jn = way_lds[j];
                p_lds[j] = p_lds[jn];
                j = jn;
            }
        }
        __syncthreads();
        prow0 = p_lds[c0]; uprow0 = u_lds[prow0];
        prow1 = p_lds[c1]; uprow1 = u_lds[prow1];
    }

    // ---- epilogue: out = softmax_row(perm * bias / sqrt(B*n)) ----
    colOf[prow0] = c0;
    colOf[prow1] = c1;
    __syncthreads();

    const float inv_norm = rsqrtf((float)B * (float)N);   // ||perm||_2 = sqrt(B*n)
    float* ob = out + (size_t)b * (N * N);
    #pragma unroll 1
    for (int r = 0; r < N; ++r) {
        int jA = colOf[r + 1];
        float s = bias[r * N + (jA - 1)] * inv_norm;
        float e = __expf(s);
        float inv_d = 1.0f / (127.0f + e);
        float av = e * inv_d;
        ob[r * N + l]      = (c0 == jA) ? av : inv_d;
        ob[r * N + l + 64] = (c1 == jA) ? av : inv_d;
    }
}

extern "C" void kernel_launch(void* const* d_in, const int* in_sizes, int n_in,
                              void* d_out, int out_size, void* d_ws, size_t ws_size,
                              hipStream_t stream) {
    const float* x    = (const float*)d_in[0];
    const float* bias = (const float*)d_in[1];
    float* out = (float*)d_out;
    int B = in_sizes[0] / (N * N);
    hipLaunchKernelGGL(lsa_solve_kernel, dim3(B), dim3(64), 0, stream, x, bias, out, B);
}

// Round 4
// 348.055 us; speedup vs baseline: 3.9372x; 3.9372x over previous
//
#include <hip/hip_runtime.h>
#include <hip/hip_fp16.h>

#define N 128
#define INF_ 1e9f
typedef unsigned long long ull;

// float -> order-preserving u32 (ascending); our NaN marker sorts above all finite
__device__ __forceinline__ unsigned f2ord(float f) {
    unsigned b = __float_as_uint(f);
    return b ^ ((unsigned)((int)b >> 31) | 0x80000000u);
}
__device__ __forceinline__ float ord2f(unsigned k) {
    unsigned b = k ^ ((unsigned)((int)(~k) >> 31) | 0x80000000u);
    return __uint_as_float(b);
}
template <int CTRL>
__device__ __forceinline__ int dppmov(int v) {
    return __builtin_amdgcn_update_dpp(v, v, CTRL, 0xF, 0xF, false);
}
__device__ __forceinline__ int rl(int v, int lane) { return __builtin_amdgcn_readlane(v, lane); }

// 64-bit keyed min-merge over DPP pattern CTRL, payload uu (float)
#define SLEV(CTRL) { \
    unsigned _lo = (unsigned)dppmov<CTRL>((int)(unsigned)kc); \
    unsigned _hi = (unsigned)dppmov<CTRL>((int)(unsigned)(kc >> 32)); \
    int _ou = dppmov<CTRL>(__float_as_int(uu)); \
    ull _okc = ((ull)_hi << 32) | _lo; \
    if (_okc < kc) { kc = _okc; uu = __int_as_float(_ou); } \
}
// payload-free variant
#define FLEV(CTRL) { \
    unsigned _lo = (unsigned)dppmov<CTRL>((int)(unsigned)kc); \
    unsigned _hi = (unsigned)dppmov<CTRL>((int)(unsigned)(kc >> 32)); \
    ull _okc = ((ull)_hi << 32) | _lo; \
    if (_okc < kc) kc = _okc; \
}

// One batch per 64-lane wave. Lane l owns columns c0=l+1, c1=l+65 (1-based).
__global__ void __launch_bounds__(64) lsa_solve_kernel(
        const float* __restrict__ x, const float* __restrict__ bias,
        float* __restrict__ out, int B) {
    __shared__ unsigned Cs[N][64];       // packed fp16 costs (= -x)
    __shared__ float u_lds[N + 1];
    __shared__ int   p_lds[N + 1];       // p[j] = row assigned to col j, 0 = free
    __shared__ int   colOf[N + 1];       // row -> col (0 = free row)
    __shared__ int   freeQ[N + 1];       // claim arbitration, then free-row queue

    const int b = blockIdx.x;
    const int l = threadIdx.x;
    const int c0 = l + 1, c1 = l + 65;
    const ull mlt = (1ull << l) - 1;
    const float* xb = x + (size_t)b * (N * N);

    // ---- stage costs into LDS (coalesced, fp16-packed) ----
    #pragma unroll 4
    for (int r = 0; r < N; ++r) {
        float a0 = xb[r * N + l];
        float a1 = xb[r * N + l + 64];
        __half2 h = __floats2half2_rn(-a0, -a1);   // minimize -x
        Cs[r][l] = __builtin_bit_cast(unsigned, h);
    }
    u_lds[l] = 0.f;  u_lds[l + 64] = 0.f;
    p_lds[c0] = 0;   p_lds[c1] = 0;
    colOf[c0] = 0;   colOf[c1] = 0;
    freeQ[l] = 0x7FFFFFFF; freeQ[l + 64] = 0x7FFFFFFF;
    if (l == 0) { u_lds[128] = 0.f; p_lds[0] = 0; colOf[0] = 0; freeQ[128] = 0x7FFFFFFF; }
    __syncthreads();

    // ---- Phase A: column reduction + greedy claim ----
    float m0 = INF_, m1 = INF_; int am0 = 1, am1 = 1;
    #pragma unroll 1
    for (int r = 0; r < N; ++r) {
        __half2 h = __builtin_bit_cast(__half2, Cs[r][l]);
        float f0 = __low2float(h), f1 = __high2float(h);
        if (f0 < m0) { m0 = f0; am0 = r + 1; }
        if (f1 < m1) { m1 = f1; am1 = r + 1; }
    }
    float v0r = m0, v1r = m1;            // v[j] = column minimum
    atomicMin(&freeQ[am0], c0);          // freeQ doubles as rowOwner here
    atomicMin(&freeQ[am1], c1);
    __syncthreads();
    int prow0 = (freeQ[am0] == c0) ? am0 : 0;
    int prow1 = (freeQ[am1] == c1) ? am1 : 0;
    p_lds[c0] = prow0;
    p_lds[c1] = prow1;
    if (prow0) colOf[am0] = c0;
    if (prow1) colOf[am1] = c1;
    __syncthreads();

    // ---- build free-row queue ----
    int nf;
    {
        int fA = (colOf[c0] == 0);       // colOf indexed by row; rows l+1, l+65
        int fB = (colOf[c1] == 0);
        ull bA = __ballot(fA), bB = __ballot(fB);
        int nA = __popcll(bA);
        if (fA) freeQ[__popcll(bA & mlt)] = c0;
        if (fB) freeQ[nA + __popcll(bB & mlt)] = c1;
        nf = nA + __popcll(bB);
    }
    __syncthreads();
    int qv0 = freeQ[l], qv1 = freeQ[l + 64];

    // ---- Phase F: free-row row reduction (bounded; no displacement) ----
    // u[i] = min_j (C[i][j] - v[j]); claim argmin col iff free (tight edge).
    #pragma unroll 1
    for (int fi = 0; fi < nf; ++fi) {
        int sl = fi & 63;
        int ia = rl(qv0, sl), ib = rl(qv1, sl);
        const int i = (fi < 64) ? ia : ib;
        __half2 h = __builtin_bit_cast(__half2, Cs[i - 1][l]);
        float rc0 = __low2float(h)  - v0r;
        float rc1 = __high2float(h) - v1r;
        ull kc0 = ((ull)f2ord(rc0) << 32) | (unsigned)(c0 << 8);
        ull kc1 = ((ull)f2ord(rc1) << 32) | (unsigned)(c1 << 8);
        ull kc = (kc1 < kc0) ? kc1 : kc0;
        FLEV(0x121) FLEV(0x122) FLEV(0x124) FLEV(0x128) FLEV(0x142) FLEV(0x143)
        unsigned kw = (unsigned)rl((int)(unsigned)(kc >> 32), 63);
        unsigned cw = (unsigned)rl((int)(unsigned)kc, 63);
        int jm = (int)(cw >> 8);
        float mn = ord2f(kw);
        if (l == 0) {
            u_lds[i] = mn;                                 // feasible, pre-paid first level
            if (p_lds[jm] == 0) { p_lds[jm] = i; colOf[i] = jm; }
        }
    }
    __syncthreads();

    prow0 = p_lds[c0]; prow1 = p_lds[c1];
    float uprow0 = u_lds[prow0], uprow1 = u_lds[prow1];

    // ---- rebuild free-row queue for SAP ----
    {
        int fA = (colOf[c0] == 0);
        int fB = (colOf[c1] == 0);
        ull bA = __ballot(fA), bB = __ballot(fB);
        int nA = __popcll(bA);
        if (fA) freeQ[__popcll(bA & mlt)] = c0;
        if (fB) freeQ[nA + __popcll(bB & mlt)] = c1;
        nf = nA + __popcll(bB);
    }
    __syncthreads();
    qv0 = freeQ[l]; qv1 = freeQ[l + 64];

    // ---- Phase E: SAP augmentation for remaining free rows ----
    #pragma unroll 1
    for (int fi = 0; fi < nf; ++fi) {
        int sl = fi & 63;
        int ia = rl(qv0, sl), ib = rl(qv1, sl);
        const int i = (fi < 64) ? ia : ib;

        float dist0 = INF_, dist1 = INF_;             // absolute distances (minv + cum)
        int   way0 = 0, way1 = 0;
        float cumAt0 = 0.f, cumAt1 = 0.f;
        float cum = 0.f;
        float base = -u_lds[i];                       // base = cum - u[i0]; root u preset
        int   j0 = 0, i0 = i;
        const unsigned lo0 = (unsigned)((c0 << 8) | prow0);
        const unsigned lo1 = (unsigned)((c1 << 8) | prow1);

        #pragma unroll 1
        for (int it = 0; it <= N; ++it) {
            if (c0 == j0) { cumAt0 = cum; dist0 = __int_as_float(0x7FC00000); }
            if (c1 == j0) { cumAt1 = cum; dist1 = __int_as_float(0x7FC00000); }

            __half2 h = __builtin_bit_cast(__half2, Cs[i0 - 1][l]);
            float cand0 = __low2float(h)  - v0r + base;   // C - u[i0] - v[j] + cum
            float cand1 = __high2float(h) - v1r + base;
            if (cand0 < dist0) { dist0 = cand0; way0 = j0; }
            if (cand1 < dist1) { dist1 = cand1; way1 = j0; }

            ull kc0 = ((ull)f2ord(dist0) << 32) | lo0;
            ull kc1 = ((ull)f2ord(dist1) << 32) | lo1;
            ull kc; float uu;
            if (kc1 < kc0) { kc = kc1; uu = uprow1; } else { kc = kc0; uu = uprow0; }
            SLEV(0x121) SLEV(0x122) SLEV(0x124) SLEV(0x128) SLEV(0x142) SLEV(0x143)

            unsigned kw = (unsigned)rl((int)(unsigned)(kc >> 32), 63);
            unsigned cw = (unsigned)rl((int)(unsigned)kc, 63);
            int      uw = rl(__float_as_int(uu), 63);
            cum  = ord2f(kw);
            j0   = (int)(cw >> 8);
            i0   = (int)(cw & 0xFF);
            base = cum - __int_as_float(uw);
            if (i0 == 0) break;                        // reached a free column
        }

        // deferred dual updates (use pre-walk prow)
        bool used0 = (__float_as_uint(dist0) == 0x7FC00000u);
        bool used1 = (__float_as_uint(dist1) == 0x7FC00000u);
        if (used0) { float dv = cum - cumAt0; v0r -= dv; u_lds[prow0] += dv; }
        if (used1) { float dv = cum - cumAt1; v1r -= dv; u_lds[prow1] += dv; }
        if (l == 0) u_lds[i] += cum;                   // root row
        __syncthreads();

        // register-resident augmenting-path walk (uniform scalar control)
        int j = j0;
        #pragma unroll 1
        while (j != 0) {
            int slw = (j - 1) & 63;
            int w0 = rl(way0, slw), w1 = rl(way1, slw);
            int jn = (j <= 64) ? w0 : w1;
            int slp = (jn - 1) & 63;
            int p0 = rl(prow0, slp), p1 = rl(prow1, slp);
            int pnew = (jn == 0) ? i : ((jn <= 64) ? p0 : p1);
            if (c0 == j) prow0 = pnew;
            if (c1 == j) prow1 = pnew;
            j = jn;
        }
        uprow0 = u_lds[prow0];
        uprow1 = u_lds[prow1];
    }

    // ---- epilogue: out = softmax_row(perm * bias / sqrt(B*n)) ----
    colOf[prow0] = c0;
    colOf[prow1] = c1;
    __syncthreads();

    const float inv_norm = rsqrtf((float)B * (float)N);   // ||perm||_2 = sqrt(B*n)
    float* ob = out + (size_t)b * (N * N);
    #pragma unroll 1
    for (int r = 0; r < N; ++r) {
        int jA = colOf[r + 1];
        float s = bias[r * N + (jA - 1)] * inv_norm;
        float e = __expf(s);
        float inv_d = 1.0f / (127.0f + e);
        float av = e * inv_d;
        ob[r * N + l]      = (c0 == jA) ? av : inv_d;
        ob[r * N + l + 64] = (c1 == jA) ? av : inv_d;
    }
}

extern "C" void kernel_launch(void* const* d_in, const int* in_sizes, int n_in,
                              void* d_out, int out_size, void* d_ws, size_t ws_size,
                              hipStream_t stream) {
    const float* x    = (const float*)d_in[0];
    const float* bias = (const float*)d_in[1];
    float* out = (float*)d_out;
    int B = in_sizes[0] / (N * N);
    hipLaunchKernelGGL(lsa_solve_kernel, dim3(B), dim3(64), 0, stream, x, bias, out, B);
}

// Round 5
// 325.028 us; speedup vs baseline: 4.2162x; 1.0708x over previous
//
#include <hip/hip_runtime.h>
#include <hip/hip_fp16.h>

#define N 128
#define INF_ 1e9f
typedef unsigned long long ull;

// float -> order-preserving u32 (ascending); NaN marker sorts above all finite
__device__ __forceinline__ unsigned f2ord(float f) {
    unsigned b = __float_as_uint(f);
    return b ^ ((unsigned)((int)b >> 31) | 0x80000000u);
}
__device__ __forceinline__ float ord2f(unsigned k) {
    unsigned b = k ^ ((unsigned)((int)(~k) >> 31) | 0x80000000u);
    return __uint_as_float(b);
}
template <int CTRL>
__device__ __forceinline__ int dppmov(int v) {
    return __builtin_amdgcn_update_dpp(v, v, CTRL, 0xF, 0xF, false);
}
__device__ __forceinline__ int rl(int v, int lane) { return __builtin_amdgcn_readlane(v, lane); }
__device__ __forceinline__ unsigned uminu(unsigned a, unsigned b) { return a < b ? a : b; }

// min over each 16-lane group via 4 DPP row_ror levels (2 instr/level)
#define GMIN16(k) { \
    k = uminu(k, (unsigned)dppmov<0x121>((int)k)); \
    k = uminu(k, (unsigned)dppmov<0x122>((int)k)); \
    k = uminu(k, (unsigned)dppmov<0x124>((int)k)); \
    k = uminu(k, (unsigned)dppmov<0x128>((int)k)); \
}

// One batch per 64-lane wave. Lane l owns CONSECUTIVE cols c0=2l+1, c1=2l+2 (1-based):
// lowest-lane == lowest-column for tie-breaks, and staging is one float2 per lane/row.
__global__ void __launch_bounds__(64) lsa_solve_kernel(
        const float* __restrict__ x, const float* __restrict__ bias,
        float* __restrict__ out, int B) {
    __shared__ unsigned Cs[N][64];       // packed fp16 costs (= -x), cols (2l, 2l+1)
    __shared__ float u_lds[N + 1];
    __shared__ int   p_lds[N + 1];       // p[j] = row assigned to col j, 0 = free
    __shared__ int   colOf[N + 1];       // row -> col (0 = free row)
    __shared__ int   freeQ[N + 1];       // claim arbitration, then free-row queue

    const int b = blockIdx.x;
    const int l = threadIdx.x;
    const int c0 = 2 * l + 1, c1 = 2 * l + 2;
    const ull mlt = (1ull << l) - 1;
    const float* xb = x + (size_t)b * (N * N);

    // ---- stage costs into LDS: one coalesced float2 per lane per row ----
    #pragma unroll 4
    for (int r = 0; r < N; ++r) {
        const float2 f = *(const float2*)&xb[r * N + 2 * l];
        __half2 h = __floats2half2_rn(-f.x, -f.y);     // minimize -x
        Cs[r][l] = __builtin_bit_cast(unsigned, h);
    }
    u_lds[l] = 0.f;   u_lds[l + 64] = 0.f;
    p_lds[c0] = 0;    p_lds[c1] = 0;
    colOf[l + 1] = 0; colOf[l + 65] = 0;
    freeQ[l] = 0x7FFFFFFF; freeQ[l + 64] = 0x7FFFFFFF;
    if (l == 0) { u_lds[128] = 0.f; p_lds[0] = 0; colOf[0] = 0; freeQ[128] = 0x7FFFFFFF; }
    __syncthreads();

    // ---- Phase A: column reduction + greedy claim (freeQ doubles as rowOwner) ----
    float m0 = INF_, m1 = INF_; int am0 = 1, am1 = 1;
    #pragma unroll 4
    for (int r = 0; r < N; ++r) {
        __half2 h = __builtin_bit_cast(__half2, Cs[r][l]);
        float f0 = __low2float(h), f1 = __high2float(h);
        if (f0 < m0) { m0 = f0; am0 = r + 1; }
        if (f1 < m1) { m1 = f1; am1 = r + 1; }
    }
    float v0r = m0, v1r = m1;            // v[j] = column minimum
    atomicMin(&freeQ[am0], c0);
    atomicMin(&freeQ[am1], c1);
    __syncthreads();
    int prow0 = (freeQ[am0] == c0) ? am0 : 0;
    int prow1 = (freeQ[am1] == c1) ? am1 : 0;
    p_lds[c0] = prow0;
    p_lds[c1] = prow1;
    if (prow0) colOf[am0] = c0;
    if (prow1) colOf[am1] = c1;
    __syncthreads();

    // ---- build free-row queue (rows l+1, l+65 per lane) ----
    int nf;
    {
        int fA = (colOf[l + 1] == 0);
        int fB = (colOf[l + 65] == 0);
        ull bA = __ballot(fA), bB = __ballot(fB);
        int nA = __popcll(bA);
        if (fA) freeQ[__popcll(bA & mlt)] = l + 1;
        if (fB) freeQ[nA + __popcll(bB & mlt)] = l + 65;
        nf = nA + __popcll(bB);
    }
    __syncthreads();
    int qv0 = freeQ[l], qv1 = freeQ[l + 64];

    // ---- Phase F: free-row row reduction (bounded; no displacement) ----
    #pragma unroll 1
    for (int fi = 0; fi < nf; ++fi) {
        int sl = fi & 63;
        const int i = (fi < 64) ? rl(qv0, sl) : rl(qv1, sl);
        __half2 h = __builtin_bit_cast(__half2, Cs[i - 1][l]);
        float rc0 = __low2float(h)  - v0r;
        float rc1 = __high2float(h) - v1r;
        unsigned k0 = f2ord(rc0), k1 = f2ord(rc1);
        unsigned kl = uminu(k0, k1);
        int isHi = (k1 < k0) ? 1 : 0;       // tie -> lo col
        unsigned kg = kl;
        GMIN16(kg)
        unsigned g0 = (unsigned)rl((int)kg, 0),  g1 = (unsigned)rl((int)kg, 16);
        unsigned g2 = (unsigned)rl((int)kg, 32), g3 = (unsigned)rl((int)kg, 48);
        unsigned gmin = uminu(uminu(g0, g1), uminu(g2, g3));
        ull bw = __ballot(kl == gmin);
        int wl = (int)__builtin_ctzll(bw);   // lowest lane = lowest col
        int hi = rl(isHi, wl);
        int jm = 2 * wl + 1 + hi;
        float mn = ord2f(gmin);
        if (l == 0) {
            u_lds[i] = mn;                   // feasible; tight on argmin col
            if (p_lds[jm] == 0) { p_lds[jm] = i; colOf[i] = jm; }
        }
    }
    __syncthreads();

    prow0 = p_lds[c0]; prow1 = p_lds[c1];
    float uprow0 = u_lds[prow0], uprow1 = u_lds[prow1];

    // ---- rebuild free-row queue for SAP ----
    {
        int fA = (colOf[l + 1] == 0);
        int fB = (colOf[l + 65] == 0);
        ull bA = __ballot(fA), bB = __ballot(fB);
        int nA = __popcll(bA);
        if (fA) freeQ[__popcll(bA & mlt)] = l + 1;
        if (fB) freeQ[nA + __popcll(bB & mlt)] = l + 65;
        nf = nA + __popcll(bB);
    }
    __syncthreads();
    qv0 = freeQ[l]; qv1 = freeQ[l + 64];

    // ---- Phase E: SAP augmentation for remaining free rows ----
    #pragma unroll 1
    for (int fi = 0; fi < nf; ++fi) {
        int sl = fi & 63;
        const int i = (fi < 64) ? rl(qv0, sl) : rl(qv1, sl);

        float dist0 = INF_, dist1 = INF_;    // absolute distances (minv + cum)
        int   way0 = 0, way1 = 0;
        float cumAt0 = 0.f, cumAt1 = 0.f;
        float cum = 0.f;
        float base = -u_lds[i];              // base = cum - u[i0]
        int   j0 = 0, i0 = i;

        #pragma unroll 1
        for (int it = 0; it <= N; ++it) {
            if (c0 == j0) { cumAt0 = cum; dist0 = __int_as_float(0x7FC00000); }
            if (c1 == j0) { cumAt1 = cum; dist1 = __int_as_float(0x7FC00000); }

            __half2 h = __builtin_bit_cast(__half2, Cs[i0 - 1][l]);
            float cand0 = __low2float(h)  - v0r + base;   // C - u[i0] - v[j] + cum
            float cand1 = __high2float(h) - v1r + base;
            if (cand0 < dist0) { dist0 = cand0; way0 = j0; }
            if (cand1 < dist1) { dist1 = cand1; way1 = j0; }

            unsigned k0 = f2ord(dist0), k1 = f2ord(dist1);
            unsigned kl = uminu(k0, k1);
            int isHi = (k1 < k0) ? 1 : 0;
            unsigned kg = kl;
            GMIN16(kg)
            unsigned g0 = (unsigned)rl((int)kg, 0),  g1 = (unsigned)rl((int)kg, 16);
            unsigned g2 = (unsigned)rl((int)kg, 32), g3 = (unsigned)rl((int)kg, 48);
            unsigned gmin = uminu(uminu(g0, g1), uminu(g2, g3));
            ull bw = __ballot(kl == gmin);
            int wl = (int)__builtin_ctzll(bw);
            // parallel payload readlanes, scalar-select after (breaks dep chain)
            int hi = rl(isHi, wl);
            int pA = rl(prow0, wl), pB = rl(prow1, wl);
            int uA = rl(__float_as_int(uprow0), wl), uB = rl(__float_as_int(uprow1), wl);
            cum  = ord2f(gmin);
            j0   = 2 * wl + 1 + hi;
            i0   = hi ? pB : pA;
            base = cum - __int_as_float(hi ? uB : uA);
            if (i0 == 0) break;              // reached a free column
        }

        // deferred dual updates (pre-walk prow; distinct rows -> no LDS races)
        bool used0 = (__float_as_uint(dist0) == 0x7FC00000u);
        bool used1 = (__float_as_uint(dist1) == 0x7FC00000u);
        if (used0) { float dv = cum - cumAt0; v0r -= dv; u_lds[prow0] += dv; }
        if (used1) { float dv = cum - cumAt1; v1r -= dv; u_lds[prow1] += dv; }
        if (l == 0) u_lds[i] += cum;         // root row
        __syncthreads();

        // register-resident augmenting-path walk (uniform scalar control)
        int j = j0;
        #pragma unroll 1
        while (j != 0) {
            int idx = j - 1, slw = idx >> 1, hib = idx & 1;
            int w0 = rl(way0, slw), w1 = rl(way1, slw);
            int jn = hib ? w1 : w0;
            int pn;
            if (jn == 0) pn = i;
            else {
                int pidx = jn - 1, slp = pidx >> 1, phb = pidx & 1;
                int p0 = rl(prow0, slp), p1 = rl(prow1, slp);
                pn = phb ? p1 : p0;
            }
            if (c0 == j) prow0 = pn;
            if (c1 == j) prow1 = pn;
            j = jn;
        }
        uprow0 = u_lds[prow0];
        uprow1 = u_lds[prow1];
    }

    // ---- epilogue: out = softmax_row(perm * bias / sqrt(B*n)), float2 stores ----
    colOf[prow0] = c0;
    colOf[prow1] = c1;
    __syncthreads();

    const float inv_norm = rsqrtf((float)B * (float)N);   // ||perm||_2 = sqrt(B*n)
    float* ob = out + (size_t)b * (N * N);
    #pragma unroll 2
    for (int r = 0; r < N; ++r) {
        int jA = __builtin_amdgcn_readfirstlane(colOf[r + 1]);
        float s = bias[r * N + (jA - 1)] * inv_norm;
        float e = __expf(s);
        float inv_d = 1.0f / (127.0f + e);
        float av = e * inv_d;
        float2 w;
        w.x = (c0 == jA) ? av : inv_d;
        w.y = (c1 == jA) ? av : inv_d;
        *(float2*)&ob[r * N + 2 * l] = w;
    }
}

extern "C" void kernel_launch(void* const* d_in, const int* in_sizes, int n_in,
                              void* d_out, int out_size, void* d_ws, size_t ws_size,
                              hipStream_t stream) {
    const float* x    = (const float*)d_in[0];
    const float* bias = (const float*)d_in[1];
    float* out = (float*)d_out;
    int B = in_sizes[0] / (N * N);
    hipLaunchKernelGGL(lsa_solve_kernel, dim3(B), dim3(64), 0, stream, x, bias, out, B);
}

// Round 6
// 308.764 us; speedup vs baseline: 4.4382x; 1.0527x over previous
//
#include <hip/hip_runtime.h>
#include <hip/hip_fp16.h>

#define N 128
#define INF_ 1e9f
typedef unsigned long long ull;

// float -> order-preserving u32 (ascending); NaN marker sorts above all finite
__device__ __forceinline__ unsigned f2ord(float f) {
    unsigned b = __float_as_uint(f);
    return b ^ ((unsigned)((int)b >> 31) | 0x80000000u);
}
__device__ __forceinline__ float ord2f(unsigned k) {
    unsigned b = k ^ ((unsigned)((int)(~k) >> 31) | 0x80000000u);
    return __uint_as_float(b);
}
template <int CTRL>
__device__ __forceinline__ int dppmov(int v) {
    return __builtin_amdgcn_update_dpp(v, v, CTRL, 0xF, 0xF, false);
}
__device__ __forceinline__ int rl(int v, int lane) { return __builtin_amdgcn_readlane(v, lane); }
__device__ __forceinline__ unsigned rlu(unsigned v, int lane) {
    return (unsigned)__builtin_amdgcn_readlane((int)v, lane);
}
__device__ __forceinline__ unsigned uminu(unsigned a, unsigned b) { return a < b ? a : b; }

// min over each 16-lane group via 4 DPP row_ror levels
#define GMIN16(k) { \
    k = uminu(k, (unsigned)dppmov<0x121>((int)k)); \
    k = uminu(k, (unsigned)dppmov<0x122>((int)k)); \
    k = uminu(k, (unsigned)dppmov<0x124>((int)k)); \
    k = uminu(k, (unsigned)dppmov<0x128>((int)k)); \
}
// finish: global min of 4 group mins (uniform in SGPRs)
#define GMINALL(k, gmin) { \
    unsigned _g0 = rlu(k, 0), _g1 = rlu(k, 16), _g2 = rlu(k, 32), _g3 = rlu(k, 48); \
    gmin = uminu(uminu(_g0, _g1), uminu(_g2, _g3)); \
}

// One batch per 64-lane wave. Lane l owns CONSECUTIVE cols c0=2l+1, c1=2l+2 (1-based):
// lowest-lane == lowest-column for tie-breaks; assignment p[] lives in lane registers.
__global__ void __launch_bounds__(64) lsa_solve_kernel(
        const float* __restrict__ x, const float* __restrict__ bias,
        float* __restrict__ out, int B) {
    __shared__ unsigned Cs[N][64];       // packed fp16 costs (= -x), cols (2l, 2l+1)
    __shared__ float u_lds[N + 1];
    __shared__ int   colOf[N + 1];       // row -> col (0 = free row)
    __shared__ int   freeQ[N + 1];       // claim arbitration, then free-row queue

    const int b = blockIdx.x;
    const int l = threadIdx.x;
    const int c0 = 2 * l + 1, c1 = 2 * l + 2;
    const ull mlt = (1ull << l) - 1;
    const float* xb = x + (size_t)b * (N * N);

    // ---- stage costs into LDS: one coalesced float2 per lane per row ----
    #pragma unroll 4
    for (int r = 0; r < N; ++r) {
        const float2 f = *(const float2*)&xb[r * N + 2 * l];
        __half2 h = __floats2half2_rn(-f.x, -f.y);     // minimize -x
        Cs[r][l] = __builtin_bit_cast(unsigned, h);
    }
    u_lds[l] = 0.f;   u_lds[l + 64] = 0.f;
    colOf[l + 1] = 0; colOf[l + 65] = 0;
    freeQ[l] = 0x7FFFFFFF; freeQ[l + 64] = 0x7FFFFFFF;
    if (l == 0) { u_lds[128] = 0.f; colOf[0] = 0; freeQ[128] = 0x7FFFFFFF; }
    __syncthreads();

    // ---- Phase A: column reduction + greedy claim (freeQ doubles as rowOwner) ----
    float m0 = INF_, m1 = INF_; int am0 = 1, am1 = 1;
    #pragma unroll 4
    for (int r = 0; r < N; ++r) {
        __half2 h = __builtin_bit_cast(__half2, Cs[r][l]);
        float f0 = __low2float(h), f1 = __high2float(h);
        if (f0 < m0) { m0 = f0; am0 = r + 1; }
        if (f1 < m1) { m1 = f1; am1 = r + 1; }
    }
    float v0r = m0, v1r = m1;            // v[j] = column minimum
    atomicMin(&freeQ[am0], c0);
    atomicMin(&freeQ[am1], c1);
    __syncthreads();
    int prow0 = (freeQ[am0] == c0) ? am0 : 0;   // p[c0], p[c1] in registers
    int prow1 = (freeQ[am1] == c1) ? am1 : 0;
    if (prow0) colOf[am0] = c0;
    if (prow1) colOf[am1] = c1;
    __syncthreads();

    // ---- Phase B: reduction transfer (Jacobi reads old v; deferred distinct-col writes) ----
    {
        float pend0 = 0.f, pend1 = 0.f;
        #pragma unroll 2
        for (int r = 1; r <= N; ++r) {
            int j1 = __builtin_amdgcn_readfirstlane(colOf[r]);
            __half2 h = __builtin_bit_cast(__half2, Cs[r - 1][l]);
            float rc0 = __low2float(h)  - v0r;
            float rc1 = __high2float(h) - v1r;
            if (c0 == j1) rc0 = INF_;
            if (c1 == j1) rc1 = INF_;
            unsigned k = uminu(f2ord(rc0), f2ord(rc1));
            GMIN16(k)
            unsigned gmin; GMINALL(k, gmin)
            float m2 = ord2f(gmin);
            if (j1 != 0) {
                if (c0 == j1) pend0 = m2;
                if (c1 == j1) pend1 = m2;
            }
        }
        v0r -= pend0; v1r -= pend1;
    }

    // ---- build free-row queue (rows l+1, l+65 per lane) ----
    int nf;
    {
        int fA = (colOf[l + 1] == 0);
        int fB = (colOf[l + 65] == 0);
        ull bA = __ballot(fA), bB = __ballot(fB);
        int nA = __popcll(bA);
        if (fA) freeQ[__popcll(bA & mlt)] = l + 1;
        if (fB) freeQ[nA + __popcll(bB & mlt)] = l + 65;
        nf = nA + __popcll(bB);
    }
    __syncthreads();

    // ---- Phase C': bounded augmenting row reduction (2 passes, NO in-pass reprocess) ----
    {
        int prv = nf;
        #pragma unroll 1
        for (int pass = 0; pass < 2 && prv > 0; ++pass) {
            int wr = 0;
            #pragma unroll 1
            for (int kk = 0; kk < prv; ++kk) {
                const int i = __builtin_amdgcn_readfirstlane(freeQ[kk]);
                __half2 h = __builtin_bit_cast(__half2, Cs[i - 1][l]);
                float rc0 = __low2float(h)  - v0r;
                float rc1 = __high2float(h) - v1r;
                unsigned k0 = f2ord(rc0), k1 = f2ord(rc1);
                unsigned klmin = uminu(k0, k1);
                int isHi = (k1 < k0) ? 1 : 0;          // tie -> low col
                unsigned kg = klmin;
                GMIN16(kg)
                unsigned gmin; GMINALL(kg, gmin)
                ull bw = __ballot(klmin == gmin);
                int wl = (int)__builtin_ctzll(bw);
                int hi1 = rl(isHi, wl);
                int j1 = 2 * wl + 1 + hi1;
                // global second-best: lane wl contributes its other key, rest their min
                unsigned oth = (l == wl) ? (hi1 ? k0 : k1) : klmin;
                unsigned kg2 = oth;
                GMIN16(kg2)
                unsigned m2o; GMINALL(kg2, m2o)
                if (gmin < m2o) {
                    float d = ord2f(m2o) - ord2f(gmin);
                    if (c0 == j1) v0r -= d;            // v only decreases
                    if (c1 == j1) v1r -= d;
                } else {
                    // exact tie: if j1 occupied, take a second-best column instead
                    int sl1 = (j1 - 1) >> 1;
                    int pj1 = ((j1 - 1) & 1) ? rl(prow1, sl1) : rl(prow0, sl1);
                    if (pj1 != 0) {
                        ull bw2 = __ballot(oth == m2o);
                        int wl2 = (int)__builtin_ctzll(bw2);
                        int hi2 = (wl2 == wl) ? (hi1 ^ 1) : rl(isHi, wl2);
                        j1 = 2 * wl2 + 1 + hi2;
                    }
                }
                int slj = (j1 - 1) >> 1;
                int inc = ((j1 - 1) & 1) ? rl(prow1, slj) : rl(prow0, slj);
                if (c0 == j1) prow0 = i;
                if (c1 == j1) prow1 = i;
                if (l == 0) {
                    colOf[i] = j1;
                    if (inc != 0) { colOf[inc] = 0; freeQ[wr] = inc; }  // next pass only
                }
                if (inc != 0) ++wr;
            }
            prv = wr;                                   // hard-bounded: <= nf per pass
            __syncthreads();
        }
    }

    // ---- rebuild free-row queue ----
    {
        int fA = (colOf[l + 1] == 0);
        int fB = (colOf[l + 65] == 0);
        ull bA = __ballot(fA), bB = __ballot(fB);
        int nA = __popcll(bA);
        if (fA) freeQ[__popcll(bA & mlt)] = l + 1;
        if (fB) freeQ[nA + __popcll(bB & mlt)] = l + 65;
        nf = nA + __popcll(bB);
    }
    __syncthreads();
    int qv0 = freeQ[l], qv1 = freeQ[l + 64];

    // ---- Phase F: free-row row reduction (sets u; claims argmin col iff free) ----
    #pragma unroll 1
    for (int fi = 0; fi < nf; ++fi) {
        int sl = fi & 63;
        const int i = (fi < 64) ? rl(qv0, sl) : rl(qv1, sl);
        __half2 h = __builtin_bit_cast(__half2, Cs[i - 1][l]);
        float rc0 = __low2float(h)  - v0r;
        float rc1 = __high2float(h) - v1r;
        unsigned k0 = f2ord(rc0), k1 = f2ord(rc1);
        unsigned kl = uminu(k0, k1);
        int isHi = (k1 < k0) ? 1 : 0;
        unsigned kg = kl;
        GMIN16(kg)
        unsigned gmin; GMINALL(kg, gmin)
        ull bw = __ballot(kl == gmin);
        int wl = (int)__builtin_ctzll(bw);
        int hi = rl(isHi, wl);
        int jm = 2 * wl + 1 + hi;
        if (l == 0) u_lds[i] = ord2f(gmin);             // feasible; prepaid first level
        int slm = (jm - 1) >> 1;
        int pm = ((jm - 1) & 1) ? rl(prow1, slm) : rl(prow0, slm);
        if (pm == 0) {
            if (c0 == jm) prow0 = i;
            if (c1 == jm) prow1 = i;
            if (l == 0) colOf[i] = jm;
        }
    }
    __syncthreads();

    // ---- Phase D: u = C - v on assigned pairs (column-owner lanes; 2-way LDS, free) ----
    if (prow0) {
        __half2 h = __builtin_bit_cast(__half2, Cs[prow0 - 1][l]);
        u_lds[prow0] = __low2float(h) - v0r;
    }
    if (prow1) {
        __half2 h = __builtin_bit_cast(__half2, Cs[prow1 - 1][l]);
        u_lds[prow1] = __high2float(h) - v1r;
    }
    __syncthreads();

    // ---- rebuild free-row queue for SAP ----
    {
        int fA = (colOf[l + 1] == 0);
        int fB = (colOf[l + 65] == 0);
        ull bA = __ballot(fA), bB = __ballot(fB);
        int nA = __popcll(bA);
        if (fA) freeQ[__popcll(bA & mlt)] = l + 1;
        if (fB) freeQ[nA + __popcll(bB & mlt)] = l + 65;
        nf = nA + __popcll(bB);
    }
    __syncthreads();
    qv0 = freeQ[l]; qv1 = freeQ[l + 64];
    float uprow0 = u_lds[prow0], uprow1 = u_lds[prow1];

    // ---- Phase E: SAP augmentation for remaining free rows ----
    #pragma unroll 1
    for (int fi = 0; fi < nf; ++fi) {
        int sl = fi & 63;
        const int i = (fi < 64) ? rl(qv0, sl) : rl(qv1, sl);

        float dist0 = INF_, dist1 = INF_;    // absolute distances (minv + cum)
        int   way0 = 0, way1 = 0;
        float cumAt0 = 0.f, cumAt1 = 0.f;
        float cum = 0.f;
        float base = -u_lds[i];              // base = cum - u[i0]
        int   j0 = 0, i0 = i;

        #pragma unroll 1
        for (int it = 0; it <= N; ++it) {
            if (c0 == j0) { cumAt0 = cum; dist0 = __int_as_float(0x7FC00000); }
            if (c1 == j0) { cumAt1 = cum; dist1 = __int_as_float(0x7FC00000); }

            __half2 h = __builtin_bit_cast(__half2, Cs[i0 - 1][l]);
            float cand0 = __low2float(h)  - v0r + base;   // C - u[i0] - v[j] + cum
            float cand1 = __high2float(h) - v1r + base;
            if (cand0 < dist0) { dist0 = cand0; way0 = j0; }
            if (cand1 < dist1) { dist1 = cand1; way1 = j0; }

            unsigned k0 = f2ord(dist0), k1 = f2ord(dist1);
            unsigned kl = uminu(k0, k1);
            int isHi = (k1 < k0) ? 1 : 0;
            unsigned kg = kl;
            GMIN16(kg)
            unsigned gmin; GMINALL(kg, gmin)
            ull bw = __ballot(kl == gmin);
            int wl = (int)__builtin_ctzll(bw);
            // parallel payload readlanes, scalar-select after (breaks dep chain)
            int hi = rl(isHi, wl);
            int pA = rl(prow0, wl), pB = rl(prow1, wl);
            int uA = rl(__float_as_int(uprow0), wl), uB = rl(__float_as_int(uprow1), wl);
            cum  = ord2f(gmin);
            j0   = 2 * wl + 1 + hi;
            i0   = hi ? pB : pA;
            base = cum - __int_as_float(hi ? uB : uA);
            if (i0 == 0) break;              // reached a free column
        }

        // deferred dual updates (pre-walk prow; distinct rows -> no LDS races)
        bool used0 = (__float_as_uint(dist0) == 0x7FC00000u);
        bool used1 = (__float_as_uint(dist1) == 0x7FC00000u);
        if (used0) { float dv = cum - cumAt0; v0r -= dv; u_lds[prow0] += dv; }
        if (used1) { float dv = cum - cumAt1; v1r -= dv; u_lds[prow1] += dv; }
        if (l == 0) u_lds[i] += cum;         // root row
        __syncthreads();

        // register-resident augmenting-path walk (uniform scalar control)
        int j = j0;
        #pragma unroll 1
        while (j != 0) {
            int idx = j - 1, slw = idx >> 1, hib = idx & 1;
            int w0 = rl(way0, slw), w1 = rl(way1, slw);
            int jn = hib ? w1 : w0;
            int pn;
            if (jn == 0) pn = i;
            else {
                int pidx = jn - 1, slp = pidx >> 1, phb = pidx & 1;
                int p0 = rl(prow0, slp), p1 = rl(prow1, slp);
                pn = phb ? p1 : p0;
            }
            if (c0 == j) prow0 = pn;
            if (c1 == j) prow1 = pn;
            j = jn;
        }
        uprow0 = u_lds[prow0];
        uprow1 = u_lds[prow1];
    }

    // ---- epilogue: out = softmax_row(perm * bias / sqrt(B*n)), float2 stores ----
    colOf[prow0] = c0;
    colOf[prow1] = c1;
    __syncthreads();

    const float inv_norm = rsqrtf((float)B * (float)N);   // ||perm||_2 = sqrt(B*n)
    float* ob = out + (size_t)b * (N * N);
    #pragma unroll 2
    for (int r = 0; r < N; ++r) {
        int jA = __builtin_amdgcn_readfirstlane(colOf[r + 1]);
        float s = bias[r * N + (jA - 1)] * inv_norm;
        float e = __expf(s);
        float inv_d = 1.0f / (127.0f + e);
        float av = e * inv_d;
        float2 w;
        w.x = (c0 == jA) ? av : inv_d;
        w.y = (c1 == jA) ? av : inv_d;
        *(float2*)&ob[r * N + 2 * l] = w;
    }
}

extern "C" void kernel_launch(void* const* d_in, const int* in_sizes, int n_in,
                              void* d_out, int out_size, void* d_ws, size_t ws_size,
                              hipStream_t stream) {
    const float* x    = (const float*)d_in[0];
    const float* bias = (const float*)d_in[1];
    float* out = (float*)d_out;
    int B = in_sizes[0] / (N * N);
    hipLaunchKernelGGL(lsa_solve_kernel, dim3(B), dim3(64), 0, stream, x, bias, out, B);
}